// Round 11
// baseline (214.932 us; speedup 1.0000x reference)
//
#include <hip/hip_runtime.h>
#include <cstdint>
#include <cstddef>

// Problem constants (fixed by the reference)
#define N_ROWS 4096
#define DIM    512
#define NCLS   30000
#define BM 256
#define BN 256
#define BK 32
#define NT2  118                    // ceil(30000/256) N-tiles
#define CPAD (NT2 * 256)            // 30208, padded classes (zero rows)
#define SPT 2                       // N-tiles per block strip
#define NSTRIPS (NT2 / SPT)         // 59
#define NS  (SPT * (DIM / BK))      // 32 K-steps per block

typedef float  f32x4  __attribute__((ext_vector_type(4)));
typedef short  bf16x8 __attribute__((ext_vector_type(8)));
typedef unsigned int   u32;
typedef unsigned short u16;

// ---- workspace layout (bytes) ----
#define WB_BYTES   ((size_t)CPAD * DIM * 2)     // 30,932,992
#define EB_BYTES   ((size_t)N_ROWS * DIM * 2)   //  4,194,304
#define PS_BYTES   ((size_t)NT2 * N_ROWS * 4)   //  1,933,312
#define CT_BYTES   ((size_t)N_ROWS * 4)
#define BL_BYTES   (64 * 4)
#define LAB_BYTES  ((size_t)N_ROWS * 4)

#define CLIP_HI ( 1.0f - 1e-7f)
#define CLIP_LO (-1.0f + 1e-7f)
#define COSM 0.8775825618903728f    // cos(0.5)
#define SINM 0.4794255386042030f    // sin(0.5)
#define K1   92.33248261972189f     // 64*log2(e): exp(64c-64) = 2^((c-1)*K1)

__device__ __forceinline__ u16 f2bf(float f) {  // RNE float->bf16
  u32 x = __builtin_bit_cast(u32, f);
  x += 0x7fffu + ((x >> 16) & 1u);
  return (u16)(x >> 16);
}

__device__ __forceinline__ void gl_lds16(const u16* g, u16* l) {
  __builtin_amdgcn_global_load_lds((const __attribute__((address_space(1))) u32*)g,
                                   (__attribute__((address_space(3))) u32*)l,
                                   16, 0, 0);
}

// ---- label dtype probe: int64 little-endian reads as [lo,0,lo,0,...] ----
__global__ void lab_detect(const int* __restrict__ lab, int* __restrict__ flag) {
  __shared__ int s_nz;
  int tid = threadIdx.x;
  if (tid == 0) s_nz = 0;
  __syncthreads();
  int nz = 0;
  for (int i = tid; i < N_ROWS / 2; i += 1024) nz |= lab[2 * i + 1];
  if (nz) atomicOr(&s_nz, 1);
  __syncthreads();
  if (tid == 0) *flag = (s_nz == 0) ? 1 : 0;   // 1 -> int64 layout
}

__global__ void lab_fix(const int* __restrict__ lab, const int* __restrict__ flag,
                        int* __restrict__ out) {
  int i = blockIdx.x * 256 + threadIdx.x;
  out[i] = flag[0] ? lab[2 * i] : lab[i];
}

// ---- W: L2-normalize rows + cast bf16; pad rows [NCLS,CPAD) with zeros ----
__global__ void prep_w(const float* __restrict__ w, u16* __restrict__ wb) {
  int wv   = threadIdx.x >> 6;
  int lane = threadIdx.x & 63;
  int c = blockIdx.x * 4 + wv;              // one wave per class row
  u16* dst = wb + (size_t)c * DIM + lane * 8;
  if (c >= NCLS) {
    *(uint4*)dst = make_uint4(0, 0, 0, 0);
    return;
  }
  const float* src = w + (size_t)c * DIM + lane * 8;
  float4 v0 = *(const float4*)src;
  float4 v1 = *(const float4*)(src + 4);
  float a[8] = {v0.x, v0.y, v0.z, v0.w, v1.x, v1.y, v1.z, v1.w};
  float ss = 0.f;
  #pragma unroll
  for (int i = 0; i < 8; i++) ss += a[i] * a[i];
  #pragma unroll
  for (int off = 32; off; off >>= 1) ss += __shfl_xor(ss, off, 64);
  float inv = 1.0f / fmaxf(sqrtf(ss), 1e-12f);
  union { u16 h[8]; uint4 q; } pk;
  #pragma unroll
  for (int i = 0; i < 8; i++) pk.h[i] = f2bf(a[i] * inv);
  *(uint4*)dst = pk.q;
}

// ---- E: cast bf16 ----
__global__ void prep_e(const float* __restrict__ e, u16* __restrict__ eb) {
  size_t idx = ((size_t)blockIdx.x * 256 + threadIdx.x) * 8;
  float4 v0 = *(const float4*)(e + idx);
  float4 v1 = *(const float4*)(e + idx + 4);
  float a[8] = {v0.x, v0.y, v0.z, v0.w, v1.x, v1.y, v1.z, v1.w};
  union { u16 h[8]; uint4 q; } pk;
  #pragma unroll
  for (int i = 0; i < 8; i++) pk.h[i] = f2bf(a[i]);
  *(uint4*)(eb + idx) = pk.q;
}

// ---- target cosine per row, f32: dot(emb[n], w[lab[n]]/||w[lab[n]]||) ----
__global__ void tgt_k(const float* __restrict__ emb, const float* __restrict__ wts,
                      const int* __restrict__ lab, float* __restrict__ ct) {
  int w = threadIdx.x >> 6, l = threadIdx.x & 63;
  int row = blockIdx.x * 4 + w;
  int c = lab[row];
  const float* e  = emb + (size_t)row * DIM + l * 8;
  const float* wp = wts + (size_t)c   * DIM + l * 8;
  float4 e0 = *(const float4*)e,       e1 = *(const float4*)(e + 4);
  float4 w0 = *(const float4*)wp,      w1 = *(const float4*)(wp + 4);
  float dot = e0.x*w0.x + e0.y*w0.y + e0.z*w0.z + e0.w*w0.w
            + e1.x*w1.x + e1.y*w1.y + e1.z*w1.z + e1.w*w1.w;
  float ss  = w0.x*w0.x + w0.y*w0.y + w0.z*w0.z + w0.w*w0.w
            + w1.x*w1.x + w1.y*w1.y + w1.z*w1.z + w1.w*w1.w;
  #pragma unroll
  for (int off = 32; off; off >>= 1) {
    dot += __shfl_xor(dot, off, 64);
    ss  += __shfl_xor(ss,  off, 64);
  }
  if (l == 0) ct[row] = dot / fmaxf(sqrtf(ss), 1e-12f);
}

// ---- fused GEMM + clip + partial sum-exp (fixed max = 64), 256x256 tile ----
// Cross-step register double-buffer (pipe OVERLAP, not more prefetch):
// per step u: [vmcnt(0)+barrier] (waits loads issued a FULL step ago),
// stage(u+2)->buf[u&1] (tile u's buf: its frags were read last step),
// ds_read frags(u+1) into the spare register set  ||  32 MFMA on frags(u).
// Reads only ISSUE here (no lgkm wait until next step's MFMAs) -> LDS unit
// drains the read burst while the matrix pipe runs. Static buffer parity
// via 2x-unrolled loop with named frag sets (rule 20).
__global__ __launch_bounds__(512, 2) void arc_main(
    const u16* __restrict__ eb, const u16* __restrict__ wb,
    float* __restrict__ psum)
{
  __shared__ __align__(16) u16 lds[32768];   // A: 2x16KB @0, B: 2x16KB @16384
  __shared__ float ep[4][BM];
  const int t  = threadIdx.x;
  const int l  = t & 63;
  const int w  = t >> 6;
  const int wm = w >> 2, wn = w & 3;
  const int cl = l & 15, bq = l >> 4;
  const int mi    = blockIdx.x & 15;    // m inner: concurrent blocks share E
  const int strip = blockIdx.x >> 4;
  const int rowbase = mi * BM;
  const int n0s = strip * SPT;

  // frag bases; slot swizzle slot' = bq ^ ((cl>>1)&3)  (R5/R8 pattern, 0-conflict)
  const u32 so    = (u32)((bq ^ ((cl >> 1) & 3)) << 3);
  const u32 aBase = (u32)(wm * 128 + cl) * 32 + so;   // frag m at +m*512
  const u32 bBase = (u32)(wn * 64  + cl) * 32 + so;   // frag n at +n*512

  // staging: 2 chunks x 128 rows; thread t -> row c*128+(t>>2), slot t&3;
  // linear LDS dest (+t*8) + inverse-swizzled global src (same involution).
  const u32 ssl = (u32)(((t & 3) ^ ((t >> 3) & 3)) << 3);
  const u32 g0  = (u32)(t >> 2) * DIM + ssl;
  const u32 g1  = (u32)(128 + (t >> 2)) * DIM + ssl;
  const u32 t8  = (u32)t * 8;
  const u16* ebR = eb + (size_t)rowbase * DIM;

  f32x4 acc[8][4];
  #pragma unroll
  for (int m = 0; m < 8; m++)
    #pragma unroll
    for (int n = 0; n < 4; n++)
      #pragma unroll
      for (int q = 0; q < 4; q++) acc[m][n][q] = 0.f;

  // prologue: stage step 0 -> buf0, step 1 -> buf1; wait only step 0's 4
  {
    const u32 b0 = (u32)n0s * (BN * DIM);
    gl_lds16(ebR + g0,            &lds[t8]);
    gl_lds16(ebR + g1,            &lds[4096 + t8]);
    gl_lds16(wb + b0 + g0,        &lds[16384 + t8]);
    gl_lds16(wb + b0 + g1,        &lds[16384 + 4096 + t8]);
    gl_lds16(ebR + 32 + g0,       &lds[8192 + t8]);
    gl_lds16(ebR + 32 + g1,       &lds[8192 + 4096 + t8]);
    gl_lds16(wb + b0 + 32 + g0,   &lds[24576 + t8]);
    gl_lds16(wb + b0 + 32 + g1,   &lds[24576 + 4096 + t8]);
  }
  asm volatile("s_waitcnt vmcnt(4)" ::: "memory");
  __builtin_amdgcn_s_barrier();
  asm volatile("" ::: "memory");

  bf16x8 fA0[8], fB0[4], fA1[8], fB1[4];
  #pragma unroll
  for (int m = 0; m < 8; m++) fA0[m] = *(const bf16x8*)&lds[aBase + m * 512];
  #pragma unroll
  for (int n = 0; n < 4; n++) fB0[n] = *(const bf16x8*)&lds[16384 + bBase + n * 512];

  // one step: PAR = u&1. Stage(u+2)->buf[PAR]; read frags(u+1) from buf[1-PAR]
  // into FAw/FBw; 32 MFMA on FAr/FBr. Reads & MFMAs share one scheduling
  // region (no fence between) -> compiler interleaves; lgkm waits land next step.
  #define STEP(u_, PAR, FAr, FBr, FAw, FBw) do {                              \
    asm volatile("s_waitcnt vmcnt(0)" ::: "memory");                          \
    __builtin_amdgcn_s_barrier();                                             \
    asm volatile("" ::: "memory");                                            \
    if ((u_) + 2 < NS) {                                                      \
      const u32 k2_ = (u32)(((u_) + 2) & 15) * 32;                            \
      const u32 b2_ = (u32)(n0s + (((u_) + 2) >> 4)) * (BN * DIM) + k2_;      \
      gl_lds16(ebR + k2_ + g0, &lds[(PAR) * 8192 + t8]);                      \
      gl_lds16(ebR + k2_ + g1, &lds[(PAR) * 8192 + 4096 + t8]);               \
      gl_lds16(wb + b2_ + g0,  &lds[16384 + (PAR) * 8192 + t8]);              \
      gl_lds16(wb + b2_ + g1,  &lds[16384 + (PAR) * 8192 + 4096 + t8]);       \
    }                                                                         \
    {                                                                         \
      const u16* Ar_ = &lds[(1 - (PAR)) * 8192];                              \
      const u16* Br_ = &lds[16384 + (1 - (PAR)) * 8192];                      \
      _Pragma("unroll")                                                       \
      for (int m_ = 0; m_ < 8; m_++)                                          \
        FAw[m_] = *(const bf16x8*)&Ar_[aBase + m_ * 512];                     \
      _Pragma("unroll")                                                       \
      for (int n_ = 0; n_ < 4; n_++)                                          \
        FBw[n_] = *(const bf16x8*)&Br_[bBase + n_ * 512];                     \
    }                                                                         \
    __builtin_amdgcn_s_setprio(1);                                            \
    _Pragma("unroll")                                                         \
    for (int m_ = 0; m_ < 8; m_++)                                            \
      _Pragma("unroll")                                                       \
      for (int n_ = 0; n_ < 4; n_++)                                          \
        acc[m_][n_] = __builtin_amdgcn_mfma_f32_16x16x32_bf16(                \
            FAr[m_], FBr[n_], acc[m_][n_], 0, 0, 0);                          \
    __builtin_amdgcn_s_setprio(0);                                            \
  } while (0)

  for (int p = 0; p < NS / 2; p++) {
    const int u0 = 2 * p;
    STEP(u0,     0, fA0, fB0, fA1, fB1);
    STEP(u0 + 1, 1, fA1, fB1, fA0, fB0);

    if ((p & 7) == 7) {
      // epilogue for N-tile nt: clip, exp2, sum over wave's 64 cols,
      // cross-wn merge via ep, one psum row-partial per N-tile.
      const int nt = n0s + (p >> 3);
      #pragma unroll
      for (int m = 0; m < 8; m++) {
        #pragma unroll
        for (int q = 0; q < 4; q++) {
          float s = 0.f;
          #pragma unroll
          for (int n = 0; n < 4; n++) {
            float tc = __builtin_amdgcn_fmed3f(acc[m][n][q], CLIP_LO, CLIP_HI);
            s += __builtin_amdgcn_exp2f(__builtin_fmaf(tc, K1, -K1));
            acc[m][n][q] = 0.f;
          }
          s += __shfl_xor(s, 1, 64);
          s += __shfl_xor(s, 2, 64);
          s += __shfl_xor(s, 4, 64);
          s += __shfl_xor(s, 8, 64);
          if ((l & 15) == 0) ep[wn][wm * 128 + m * 16 + (l >> 4) * 4 + q] = s;
        }
      }
      __syncthreads();
      if (l < 32) {
        int r = w * 32 + l;
        float v = ep[0][r] + ep[1][r] + ep[2][r] + ep[3][r];
        psum[(size_t)nt * N_ROWS + rowbase + r] = v;
      }
      __syncthreads();
    }
  }
  #undef STEP
}

// ---- per-row LSE merge + margin swap + per-block loss sums ----
__global__ void arc_finish1(const float* __restrict__ psum, const float* __restrict__ ct,
                            float* __restrict__ bl) {
  int tid = threadIdx.x;
  int row = blockIdx.x * 256 + tid;
  float S = 0.f;
  for (int p = 0; p < NT2; p++) S += psum[(size_t)p * N_ROWS + row];
  float c  = __builtin_amdgcn_fmed3f(ct[row], CLIP_LO, CLIP_HI);
  float cm = c * COSM - sqrtf(fmaxf(1.0f - c * c, 0.0f)) * SINM;
  // swap the target's no-margin term for the margin term (both vs fixed max 64)
  float S2 = S - __builtin_amdgcn_exp2f(__builtin_fmaf(c,  K1, -K1))
               + __builtin_amdgcn_exp2f(__builtin_fmaf(cm, K1, -K1));
  float loss = 64.0f + __builtin_amdgcn_logf(S2) * 0.6931471805599453f - 64.0f * cm;
  #pragma unroll
  for (int off = 32; off; off >>= 1) loss += __shfl_xor(loss, off, 64);
  __shared__ float red[4];
  if ((tid & 63) == 0) red[tid >> 6] = loss;
  __syncthreads();
  if (tid == 0) bl[blockIdx.x] = red[0] + red[1] + red[2] + red[3];
}

__global__ void arc_finish2(const float* __restrict__ bl, float* __restrict__ out) {
  if (threadIdx.x == 0) {
    float t = 0.f;
    for (int i = 0; i < N_ROWS / 256; i++) t += bl[i];
    out[0] = t * (1.0f / (float)N_ROWS);
  }
}

extern "C" void kernel_launch(void* const* d_in, const int* in_sizes, int n_in,
                              void* d_out, int out_size, void* d_ws, size_t ws_size,
                              hipStream_t stream) {
  const float* emb   = (const float*)d_in[0];
  const int*   lab   = (const int*)d_in[1];
  const float* wts   = (const float*)d_in[2];

  char* ws = (char*)d_ws;
  u16*   wb    = (u16*)(ws);
  u16*   eb    = (u16*)(ws + WB_BYTES);
  float* psum  = (float*)(ws + WB_BYTES + EB_BYTES);
  float* ct    = (float*)(ws + WB_BYTES + EB_BYTES + PS_BYTES);
  float* bl    = (float*)(ws + WB_BYTES + EB_BYTES + PS_BYTES + CT_BYTES);
  int*   lab32 = (int*)  (ws + WB_BYTES + EB_BYTES + PS_BYTES + CT_BYTES + BL_BYTES);
  int*   flag  = (int*)  (ws + WB_BYTES + EB_BYTES + PS_BYTES + CT_BYTES + BL_BYTES + LAB_BYTES);
  // total ~37.1 MiB of d_ws assumed available

  lab_detect<<<dim3(1), dim3(1024), 0, stream>>>(lab, flag);
  lab_fix<<<dim3(N_ROWS / 256), dim3(256), 0, stream>>>(lab, flag, lab32);
  prep_w<<<dim3(CPAD / 4), dim3(256), 0, stream>>>(wts, wb);
  prep_e<<<dim3((N_ROWS * DIM / 8) / 256), dim3(256), 0, stream>>>(emb, eb);
  tgt_k<<<dim3(N_ROWS / 4), dim3(256), 0, stream>>>(emb, wts, lab32, ct);
  arc_main<<<dim3(16 * NSTRIPS), dim3(512), 0, stream>>>(eb, wb, psum);
  arc_finish1<<<dim3(N_ROWS / 256), dim3(256), 0, stream>>>(psum, ct, bl);
  arc_finish2<<<dim3(1), dim3(64), 0, stream>>>(bl, (float*)d_out);
}

// Round 12
// 213.127 us; speedup vs baseline: 1.0085x; 1.0085x over previous
//
#include <hip/hip_runtime.h>
#include <cstdint>
#include <cstddef>

// Problem constants (fixed by the reference)
#define N_ROWS 4096
#define DIM    512
#define NCLS   30000
#define BM 256
#define BN 256
#define BK 32
#define NT2  118                    // ceil(30000/256) N-tiles
#define CPAD (NT2 * 256)            // 30208, padded classes (zero rows)
#define SPT 2                       // N-tiles per block strip
#define NSTRIPS (NT2 / SPT)         // 59
#define NS  (SPT * (DIM / BK))      // 32 K-steps per block

typedef float  f32x4  __attribute__((ext_vector_type(4)));
typedef short  bf16x8 __attribute__((ext_vector_type(8)));
typedef unsigned int   u32;
typedef unsigned short u16;

// ---- workspace layout (bytes) ----
#define WB_BYTES   ((size_t)CPAD * DIM * 2)     // 30,932,992
#define EB_BYTES   ((size_t)N_ROWS * DIM * 2)   //  4,194,304
#define PS_BYTES   ((size_t)NT2 * N_ROWS * 4)   //  1,933,312
#define CT_BYTES   ((size_t)N_ROWS * 4)
#define BL_BYTES   (64 * 4)
#define LAB_BYTES  ((size_t)N_ROWS * 4)

#define CLIP_HI ( 1.0f - 1e-7f)
#define CLIP_LO (-1.0f + 1e-7f)
#define COSM 0.8775825618903728f    // cos(0.5)
#define SINM 0.4794255386042030f    // sin(0.5)
#define K1   92.33248261972189f     // 64*log2(e): exp(64c-64) = 2^((c-1)*K1)

__device__ __forceinline__ u16 f2bf(float f) {  // RNE float->bf16
  u32 x = __builtin_bit_cast(u32, f);
  x += 0x7fffu + ((x >> 16) & 1u);
  return (u16)(x >> 16);
}

__device__ __forceinline__ void gl_lds16(const u16* g, u16* l) {
  __builtin_amdgcn_global_load_lds((const __attribute__((address_space(1))) u32*)g,
                                   (__attribute__((address_space(3))) u32*)l,
                                   16, 0, 0);
}

// ---- label dtype probe: int64 little-endian reads as [lo,0,lo,0,...] ----
__global__ void lab_detect(const int* __restrict__ lab, int* __restrict__ flag) {
  __shared__ int s_nz;
  int tid = threadIdx.x;
  if (tid == 0) s_nz = 0;
  __syncthreads();
  int nz = 0;
  for (int i = tid; i < N_ROWS / 2; i += 1024) nz |= lab[2 * i + 1];
  if (nz) atomicOr(&s_nz, 1);
  __syncthreads();
  if (tid == 0) *flag = (s_nz == 0) ? 1 : 0;   // 1 -> int64 layout
}

__global__ void lab_fix(const int* __restrict__ lab, const int* __restrict__ flag,
                        int* __restrict__ out) {
  int i = blockIdx.x * 256 + threadIdx.x;
  out[i] = flag[0] ? lab[2 * i] : lab[i];
}

// ---- W: L2-normalize rows + cast bf16; pad rows [NCLS,CPAD) with zeros ----
__global__ void prep_w(const float* __restrict__ w, u16* __restrict__ wb) {
  int wv   = threadIdx.x >> 6;
  int lane = threadIdx.x & 63;
  int c = blockIdx.x * 4 + wv;              // one wave per class row
  u16* dst = wb + (size_t)c * DIM + lane * 8;
  if (c >= NCLS) {
    *(uint4*)dst = make_uint4(0, 0, 0, 0);
    return;
  }
  const float* src = w + (size_t)c * DIM + lane * 8;
  float4 v0 = *(const float4*)src;
  float4 v1 = *(const float4*)(src + 4);
  float a[8] = {v0.x, v0.y, v0.z, v0.w, v1.x, v1.y, v1.z, v1.w};
  float ss = 0.f;
  #pragma unroll
  for (int i = 0; i < 8; i++) ss += a[i] * a[i];
  #pragma unroll
  for (int off = 32; off; off >>= 1) ss += __shfl_xor(ss, off, 64);
  float inv = 1.0f / fmaxf(sqrtf(ss), 1e-12f);
  union { u16 h[8]; uint4 q; } pk;
  #pragma unroll
  for (int i = 0; i < 8; i++) pk.h[i] = f2bf(a[i] * inv);
  *(uint4*)dst = pk.q;
}

// ---- E: cast bf16 ----
__global__ void prep_e(const float* __restrict__ e, u16* __restrict__ eb) {
  size_t idx = ((size_t)blockIdx.x * 256 + threadIdx.x) * 8;
  float4 v0 = *(const float4*)(e + idx);
  float4 v1 = *(const float4*)(e + idx + 4);
  float a[8] = {v0.x, v0.y, v0.z, v0.w, v1.x, v1.y, v1.z, v1.w};
  union { u16 h[8]; uint4 q; } pk;
  #pragma unroll
  for (int i = 0; i < 8; i++) pk.h[i] = f2bf(a[i]);
  *(uint4*)(eb + idx) = pk.q;
}

// ---- target cosine per row, f32: dot(emb[n], w[lab[n]]/||w[lab[n]]||) ----
__global__ void tgt_k(const float* __restrict__ emb, const float* __restrict__ wts,
                      const int* __restrict__ lab, float* __restrict__ ct) {
  int w = threadIdx.x >> 6, l = threadIdx.x & 63;
  int row = blockIdx.x * 4 + w;
  int c = lab[row];
  const float* e  = emb + (size_t)row * DIM + l * 8;
  const float* wp = wts + (size_t)c   * DIM + l * 8;
  float4 e0 = *(const float4*)e,       e1 = *(const float4*)(e + 4);
  float4 w0 = *(const float4*)wp,      w1 = *(const float4*)(wp + 4);
  float dot = e0.x*w0.x + e0.y*w0.y + e0.z*w0.z + e0.w*w0.w
            + e1.x*w1.x + e1.y*w1.y + e1.z*w1.z + e1.w*w1.w;
  float ss  = w0.x*w0.x + w0.y*w0.y + w0.z*w0.z + w0.w*w0.w
            + w1.x*w1.x + w1.y*w1.y + w1.z*w1.z + w1.w*w1.w;
  #pragma unroll
  for (int off = 32; off; off >>= 1) {
    dot += __shfl_xor(dot, off, 64);
    ss  += __shfl_xor(ss,  off, 64);
  }
  if (l == 0) ct[row] = dot / fmaxf(sqrtf(ss), 1e-12f);
}

// ---- fused GEMM + clip + partial sum-exp (fixed max = 64), 256x256 tile ----
// R3's proven sync skeleton (1 barrier/step, stage 2-ahead, counted vmcnt(4))
// rebuilt for ZERO per-step addressing VALU:
//  - 4-buf ring + unroll-4 -> buf index (u0+j)&3 = j is COMPILE-TIME
//  - swizzle slot (r>>1)&3 is m/n-independent -> all 12 frag reads are ONE
//    base register + compile-time immediates (m*1024 / n*1024 / j*16384)
//  - staging dests const per j; sources = base + small runtime k-offset
// Layout (bytes): A bufs 4x16KB @0, B bufs 4x16KB @65536, ep 4KB @131072.
__global__ __launch_bounds__(512) void arc_main(
    const u16* __restrict__ eb, const u16* __restrict__ wb,
    float* __restrict__ psum)
{
  __shared__ __align__(16) char smem[135168];
  const int t  = threadIdx.x;
  const int l  = t & 63;
  const int w  = t >> 6;
  const int wm = w >> 2, wn = w & 3;
  const int cl = l & 15, bq = l >> 4;
  const int mi    = blockIdx.x & 15;    // m inner: concurrent blocks share E
  const int strip = blockIdx.x >> 4;
  const int rowbase = mi * BM;
  const int n0s = strip * SPT;

  // frag base addresses (bytes); slot' = bq ^ ((cl>>1)&3) — m/n-independent
  const u32 swz = (u32)((bq ^ ((cl >> 1) & 3)) << 3);
  const u32 aB  = ((u32)(wm * 128 + cl) * 32 + swz) * 2;
  const u32 bB  = 65536u + ((u32)(wn * 64 + cl) * 32 + swz) * 2;

  // staging: thread t covers rows t>>2 and 128+(t>>2), 16B slot t&3;
  // linear LDS dest + inverse-swizzled global source (same involution).
  const u32 ssl = (u32)(((t & 3) ^ ((t >> 3) & 3)) << 3);
  const u32 g0  = (u32)(t >> 2) * DIM + ssl;
  const u32 g1  = (u32)(128 + (t >> 2)) * DIM + ssl;
  const u32 tb  = (u32)t * 16;
  const u16* ebR = eb + (size_t)rowbase * DIM;
  const u16* wbS = wb + (size_t)n0s * (BN * DIM);

  f32x4 acc[8][4];
  #pragma unroll
  for (int m = 0; m < 8; m++)
    #pragma unroll
    for (int n = 0; n < 4; n++)
      #pragma unroll
      for (int q = 0; q < 4; q++) acc[m][n][q] = 0.f;

  // prologue: stage K-steps 0,1 into bufs 0,1; wait step 0's 4 only
  #pragma unroll
  for (int v = 0; v < 2; v++) {
    gl_lds16(ebR + v * 32 + g0, (u16*)(smem + v * 16384 + tb));
    gl_lds16(ebR + v * 32 + g1, (u16*)(smem + v * 16384 + 8192 + tb));
    gl_lds16(wbS + v * 32 + g0, (u16*)(smem + 65536 + v * 16384 + tb));
    gl_lds16(wbS + v * 32 + g1, (u16*)(smem + 65536 + v * 16384 + 8192 + tb));
  }
  asm volatile("s_waitcnt vmcnt(4)" ::: "memory");
  __builtin_amdgcn_s_barrier();
  asm volatile("" ::: "memory");

  for (int u0 = 0; u0 < NS; u0 += 4) {
    #pragma unroll
    for (int j = 0; j < 4; j++) {
      const int u = u0 + j;

      if (u < NS - 1) asm volatile("s_waitcnt vmcnt(4)" ::: "memory");
      else            asm volatile("s_waitcnt vmcnt(0)" ::: "memory");
      __builtin_amdgcn_s_barrier();
      asm volatile("" ::: "memory");

      // stage step u+2 into buf (j+2)&3 (its readers finished at barrier u-1)
      if (u + 2 < NS) {
        const int v = u + 2;
        const u32 ka = (u32)(v & 15) * 32;
        const u16* bsrc = wbS + (size_t)(v >> 4) * (BN * DIM) + ka;
        char* dA = smem + ((j + 2) & 3) * 16384;
        char* dB = smem + 65536 + ((j + 2) & 3) * 16384;
        gl_lds16(ebR + ka + g0, (u16*)(dA + tb));
        gl_lds16(ebR + ka + g1, (u16*)(dA + 8192 + tb));
        gl_lds16(bsrc + g0,     (u16*)(dB + tb));
        gl_lds16(bsrc + g1,     (u16*)(dB + 8192 + tb));
      }

      // frag reads: single base + compile-time immediates (buf j, frag m/n)
      bf16x8 af[8], bg[4];
      #pragma unroll
      for (int m = 0; m < 8; m++)
        af[m] = *(const bf16x8*)(smem + j * 16384 + aB + m * 1024);
      #pragma unroll
      for (int n = 0; n < 4; n++)
        bg[n] = *(const bf16x8*)(smem + j * 16384 + bB + n * 1024);

      __builtin_amdgcn_s_setprio(1);
      #pragma unroll
      for (int m = 0; m < 8; m++)
        #pragma unroll
        for (int n = 0; n < 4; n++)
          acc[m][n] = __builtin_amdgcn_mfma_f32_16x16x32_bf16(af[m], bg[n], acc[m][n], 0, 0, 0);
      __builtin_amdgcn_s_setprio(0);

      if (j == 3 && (u0 & 15) == 12) {
        // epilogue for N-tile nt (u = 15 or 31): clip, exp2, row-partials
        const int nt = n0s + (u >> 4);
        float* ep = (float*)(smem + 131072);   // [4][256]
        #pragma unroll
        for (int m = 0; m < 8; m++) {
          #pragma unroll
          for (int q = 0; q < 4; q++) {
            float s = 0.f;
            #pragma unroll
            for (int n = 0; n < 4; n++) {
              float tc = __builtin_amdgcn_fmed3f(acc[m][n][q], CLIP_LO, CLIP_HI);
              s += __builtin_amdgcn_exp2f(__builtin_fmaf(tc, K1, -K1));
              acc[m][n][q] = 0.f;
            }
            s += __shfl_xor(s, 1, 64);
            s += __shfl_xor(s, 2, 64);
            s += __shfl_xor(s, 4, 64);
            s += __shfl_xor(s, 8, 64);
            if ((l & 15) == 0) ep[wn * 256 + wm * 128 + m * 16 + (l >> 4) * 4 + q] = s;
          }
        }
        asm volatile("s_waitcnt lgkmcnt(0)" ::: "memory");
        __builtin_amdgcn_s_barrier();
        asm volatile("" ::: "memory");
        if (l < 32) {
          int r = w * 32 + l;
          float v = ep[r] + ep[256 + r] + ep[512 + r] + ep[768 + r];
          psum[(size_t)nt * N_ROWS + rowbase + r] = v;
        }
        asm volatile("" ::: "memory");
        __builtin_amdgcn_s_barrier();   // ep reads done before reuse
        asm volatile("" ::: "memory");
      }
    }
  }
}

// ---- per-row LSE merge + margin swap + per-block loss sums ----
__global__ void arc_finish1(const float* __restrict__ psum, const float* __restrict__ ct,
                            float* __restrict__ bl) {
  int tid = threadIdx.x;
  int row = blockIdx.x * 256 + tid;
  float S = 0.f;
  for (int p = 0; p < NT2; p++) S += psum[(size_t)p * N_ROWS + row];
  float c  = __builtin_amdgcn_fmed3f(ct[row], CLIP_LO, CLIP_HI);
  float cm = c * COSM - sqrtf(fmaxf(1.0f - c * c, 0.0f)) * SINM;
  // swap the target's no-margin term for the margin term (both vs fixed max 64)
  float S2 = S - __builtin_amdgcn_exp2f(__builtin_fmaf(c,  K1, -K1))
               + __builtin_amdgcn_exp2f(__builtin_fmaf(cm, K1, -K1));
  float loss = 64.0f + __builtin_amdgcn_logf(S2) * 0.6931471805599453f - 64.0f * cm;
  #pragma unroll
  for (int off = 32; off; off >>= 1) loss += __shfl_xor(loss, off, 64);
  __shared__ float red[4];
  if ((tid & 63) == 0) red[tid >> 6] = loss;
  __syncthreads();
  if (tid == 0) bl[blockIdx.x] = red[0] + red[1] + red[2] + red[3];
}

__global__ void arc_finish2(const float* __restrict__ bl, float* __restrict__ out) {
  if (threadIdx.x == 0) {
    float t = 0.f;
    for (int i = 0; i < N_ROWS / 256; i++) t += bl[i];
    out[0] = t * (1.0f / (float)N_ROWS);
  }
}

extern "C" void kernel_launch(void* const* d_in, const int* in_sizes, int n_in,
                              void* d_out, int out_size, void* d_ws, size_t ws_size,
                              hipStream_t stream) {
  const float* emb   = (const float*)d_in[0];
  const int*   lab   = (const int*)d_in[1];
  const float* wts   = (const float*)d_in[2];

  char* ws = (char*)d_ws;
  u16*   wb    = (u16*)(ws);
  u16*   eb    = (u16*)(ws + WB_BYTES);
  float* psum  = (float*)(ws + WB_BYTES + EB_BYTES);
  float* ct    = (float*)(ws + WB_BYTES + EB_BYTES + PS_BYTES);
  float* bl    = (float*)(ws + WB_BYTES + EB_BYTES + PS_BYTES + CT_BYTES);
  int*   lab32 = (int*)  (ws + WB_BYTES + EB_BYTES + PS_BYTES + CT_BYTES + BL_BYTES);
  int*   flag  = (int*)  (ws + WB_BYTES + EB_BYTES + PS_BYTES + CT_BYTES + BL_BYTES + LAB_BYTES);
  // total ~37.1 MiB of d_ws assumed available

  lab_detect<<<dim3(1), dim3(1024), 0, stream>>>(lab, flag);
  lab_fix<<<dim3(N_ROWS / 256), dim3(256), 0, stream>>>(lab, flag, lab32);
  prep_w<<<dim3(CPAD / 4), dim3(256), 0, stream>>>(wts, wb);
  prep_e<<<dim3((N_ROWS * DIM / 8) / 256), dim3(256), 0, stream>>>(emb, eb);
  tgt_k<<<dim3(N_ROWS / 4), dim3(256), 0, stream>>>(emb, wts, lab32, ct);
  arc_main<<<dim3(16 * NSTRIPS), dim3(512), 0, stream>>>(eb, wb, psum);
  arc_finish1<<<dim3(N_ROWS / 256), dim3(256), 0, stream>>>(psum, ct, bl);
  arc_finish2<<<dim3(1), dim3(64), 0, stream>>>(bl, (float*)d_out);
}